// Round 8
// baseline (1111.218 us; speedup 1.0000x reference)
//
#include <hip/hip_runtime.h>

// SDE scan: B=2048 rows, T=512 steps, FS=32, FA=16, H=64.
// R8: f/g WAVE SPLIT. Block = 128 threads = 2 waves per row:
//     wave F computes the drift MLP, wave G the diffusion MLP, in parallel.
//     Halves the per-step serial dependency chain (R7 measured 2127 cy/step
//     vs ~1160 cy VALU issue -> latency-bound at 2 waves/SIMD).
//     Bit-exact vs R7 (absmax must stay 0.0078125):
//       L1: each wave runs its own R7 chain (24-deep pk, same order).
//       L2: F runs R7's lanes<32 drift chain (redundant in both halves,
//           no shfl); G runs the lanes>=32 gpre chain. Same sigma-permuted
//           h layout, same w2 pairing, same quad order.
//       x-update: xi = fmaf(gpre, eps_c*SQRT_DT, drift) exactly as R7.
//     Cross-wave handoff via LDS with lgkm-only barriers (raw s_barrier;
//     NEVER vmcnt -> eps/a global prefetches stay in flight). 2 barriers/step.
//     Weights per wave halve (~112 regs) -> arch-VGPR resident under
//     launch_bounds(128,2) (256-reg budget).

#define SQRT_DT_F 0.22360679774997896f

typedef float v2f __attribute__((ext_vector_type(2)));
typedef float v4f __attribute__((ext_vector_type(4)));

// Packed 2x fp32 FMA: per-element fmaf semantics; lowers to v_pk_fma_f32.
#define PK(acc, s, w) (acc) = __builtin_elementwise_fma((s), (w), (acc))

__device__ __forceinline__ float fast_tanh(float y) {
    // tanh(y) = 1 - 2/(exp(2y)+1); stable at both extremes
    float e = __expf(2.0f * y);
    return 1.0f - 2.0f / (e + 1.0f);
}

__device__ __forceinline__ void wave_sync() {
    // Intra-wave DS ordering only (compiler barrier for DS class).
    __builtin_amdgcn_fence(__ATOMIC_SEQ_CST, "wavefront");
    __builtin_amdgcn_sched_barrier(0x047F);
}

__device__ __forceinline__ void block_sync_lds() {
    // Cross-wave LDS handoff: drain OUR ds queue, then workgroup barrier.
    // Deliberately no vmcnt wait (global prefetches must stay in flight).
    asm volatile("s_waitcnt lgkmcnt(0)" ::: "memory");
    __builtin_amdgcn_sched_barrier(0);
    __builtin_amdgcn_s_barrier();
    __builtin_amdgcn_sched_barrier(0);
}

__global__ __launch_bounds__(128, 2)
void sde_kernel(const float* __restrict__ in_signal,   // (B,16,512)
                const float* __restrict__ x0v,         // (B,32)
                const float* __restrict__ noise,       // (511,B,32)
                const float* __restrict__ Wf1, const float* __restrict__ bf1,
                const float* __restrict__ Wf2, const float* __restrict__ bf2,
                const float* __restrict__ Wg1, const float* __restrict__ bg1,
                const float* __restrict__ Wg2, const float* __restrict__ bg2,
                float* __restrict__ out)               // (B,32,512)
{
    const int tid    = threadIdx.x;
    const int wid    = tid >> 6;        // 0 = drift wave (F), 1 = diff wave (G)
    const int lane   = tid & 63;
    const int lane31 = lane & 31;
    const int b      = blockIdx.x;

    __shared__ __align__(16) float hbuf[2][64];    // [wid][sigma(j)]
    __shared__ __align__(16) float xbuf[32];       // broadcast x-state (G writes)
    __shared__ __align__(16) float abuf[2][4][16]; // [quad parity][tt][k] (F stages)
    __shared__ __align__(16) float dbuf[32];       // drift handoff F -> G

    // ---- per-wave weight set (halved footprint) ----
    const float* W1 = wid ? Wg1 : Wf1;
    const float* B1 = wid ? bg1 : bf1;
    const float* W2 = wid ? Wg2 : Wf2;
    const float* B2 = wid ? bg2 : bf2;

    // L1 pair k2 covers input indices (2k2, 2k2+1): pk lanes = R7 (c0,c1) chains.
    v2f w1v[24];
#pragma unroll
    for (int k2 = 0; k2 < 24; ++k2)
        w1v[k2] = v2f{W1[(2 * k2) * 64 + lane], W1[(2 * k2 + 1) * 64 + lane]};
    // L2 pair (g,i) covers h indices (8g+i, 8g+4+i): pk lanes = R7 (a,b) chains.
    v2f w2v[32];
    const float* W2p = W2 + lane31;
#pragma unroll
    for (int g = 0; g < 8; ++g)
#pragma unroll
        for (int i = 0; i < 4; ++i)
            w2v[g * 4 + i] = v2f{W2p[(8 * g + i) * 32], W2p[(8 * g + 4 + i) * 32]};

    const float b1 = B1[lane];
    const float b2 = B2[lane31];

    // sigma: position of h_j inside its 8-block so that (j, j+4) pairs are
    // adjacent in LDS (same as R7). sigma(8g+r) = 8g + ((r&3)<<1 | r>>2).
    const int sig = (lane & ~7) | ((lane & 3) << 1) | ((lane >> 2) & 1);
    float* hw_ = &hbuf[wid][sig];
    const float* hs_ = hbuf[wid];

    const float* a_base = in_signal + ((size_t)(b * 16 + (lane & 15)) << 9);
    const float* noise_lane = noise + (size_t)b * 32 + lane31;
    float* out_ptr = out + ((size_t)b * 32 + lane31) * 512;

    float eps_c = 0.f, eps_n = 0.f;
    float xq[4] = {0.f, 0.f, 0.f, 0.f};

    if (wid) {
        // G owns eps, x-state, output.
        eps_c = noise_lane[0];                 // t = 0
        eps_n = noise_lane[65536];             // t = 1
        float x_init = x0v[b * 32 + lane31];
        xbuf[lane31] = x_init;                 // 2-way same-value: free
        xq[0] = x_init;
    } else {
        // F owns a-signal staging.
        float4 a0 = *(const float4*)(a_base);
        if (lane < 16) {
            abuf[0][0][lane] = a0.x;
            abuf[0][1][lane] = a0.y;
            abuf[0][2][lane] = a0.z;
            abuf[0][3][lane] = a0.w;
        }
    }
    block_sync_lds();

#define STEP(tt) do {                                                           \
    /* G: prefetch eps for step t+2 (uniform base + lane offset) */             \
    int tf_ = tq4 + (tt) + 2; if (tf_ > 510) tf_ = 510;                         \
    float eps_f = 0.f;                                                          \
    if (wid) eps_f = noise_lane[(size_t)tf_ << 16];                             \
    /* layer-1 operands: batch LDS broadcast reads (12 ds_read_b128) */         \
    v4f sq[12];                                                                 \
    sq[0] = *(const v4f*)&ab_[tt][0];                                           \
    sq[1] = *(const v4f*)&ab_[tt][4];                                           \
    sq[2] = *(const v4f*)&ab_[tt][8];                                           \
    sq[3] = *(const v4f*)&ab_[tt][12];                                          \
    _Pragma("unroll")                                                           \
    for (int q = 0; q < 8; ++q)                                                 \
        sq[4 + q] = *(const v4f*)&xbuf[q * 4];                                  \
    /* layer 1: lane j -> h_j for this wave's net; R7 chain order, bit-exact */ \
    v2f a1 = v2f{b1, 0.f};                                                      \
    _Pragma("unroll")                                                           \
    for (int q = 0; q < 12; ++q) {                                              \
        v2f slo = sq[q].xy, shi = sq[q].zw;                                     \
        PK(a1, slo, w1v[2 * q]);                                                \
        PK(a1, shi, w1v[2 * q + 1]);                                            \
    }                                                                           \
    float hv = fast_tanh(a1.x + a1.y);                                          \
    hw_[0] = hv;                                                                \
    wave_sync();   /* intra-wave: h write before h reads */                     \
    /* layer 2: full 32-pk chain (R7 order), redundant in both halves */        \
    v2f a2 = v2f{b2, 0.f};                                                      \
    _Pragma("unroll")                                                           \
    for (int g = 0; g < 8; ++g) {                                               \
        const v4f qa = *(const v4f*)&hs_[g * 8];                                \
        const v4f qb = *(const v4f*)&hs_[g * 8 + 4];                            \
        v2f p0 = qa.xy, p1 = qa.zw, p2 = qb.xy, p3 = qb.zw;                     \
        PK(a2, p0, w2v[g * 4 + 0]);                                             \
        PK(a2, p1, w2v[g * 4 + 1]);                                             \
        PK(a2, p2, w2v[g * 4 + 2]);                                             \
        PK(a2, p3, w2v[g * 4 + 3]);                                             \
    }                                                                           \
    float res = a2.x + a2.y;   /* drift (F) or gpre (G) */                      \
    if (!wid) dbuf[lane31] = res;   /* 2-way same-value: free */                \
    block_sync_lds();               /* barrier A: drift visible to G */         \
    if (wid) {                                                                  \
        float drift = dbuf[lane31];                                             \
        float xi = fmaf(res, eps_c * SQRT_DT_F, drift);                         \
        xi = fminf(5.0f, fmaxf(-5.0f, xi));                                     \
        xbuf[lane31] = xi;          /* 2-way same-value: free */                \
        xq[((tt) + 1) & 3] = xi;                                                \
        if ((tt) == 2) {                                                        \
            if (lane < 32)                                                      \
                *(float4*)(out_ptr + tq4) =                                     \
                    make_float4(xq[0], xq[1], xq[2], xq[3]);                    \
        }                                                                       \
    }                                                                           \
    block_sync_lds();               /* barrier B: new x visible to both */      \
    eps_c = eps_n; eps_n = eps_f;                                               \
} while (0)

    // main: t = 0..507 (127 quads)
    for (int tq = 0; tq < 127; ++tq) {
        const int tq4 = tq * 4;
        const float (*ab_)[16] = abuf[tq & 1];
        float4 aq_n;
        if (!wid) aq_n = *(const float4*)(a_base + tq4 + 4);   // quad tq+1
        STEP(0);
        // F stages next quad's a-values (opposite parity; no race with reads)
        if (!wid && lane < 16) {
            float (*abn)[16] = abuf[(tq + 1) & 1];
            abn[0][lane] = aq_n.x;
            abn[1][lane] = aq_n.y;
            abn[2][lane] = aq_n.z;
            abn[3][lane] = aq_n.w;
        }
        STEP(1); STEP(2); STEP(3);
    }
    // tail: t = 508, 509, 510  (store of [508..511] fires at tt==2)
    {
        const int tq4 = 508;
        const float (*ab_)[16] = abuf[127 & 1];
        STEP(0); STEP(1); STEP(2);
    }
#undef STEP
}

extern "C" void kernel_launch(void* const* d_in, const int* in_sizes, int n_in,
                              void* d_out, int out_size, void* d_ws, size_t ws_size,
                              hipStream_t stream) {
    // inputs: 0 ts(unused), 1 in_signal, 2 x0, 3 noise, 4 Wf1, 5 bf1, 6 Wf2,
    //         7 bf2, 8 Wg1, 9 bg1, 10 Wg2, 11 bg2
    const float* in_signal = (const float*)d_in[1];
    const float* x0v   = (const float*)d_in[2];
    const float* noise = (const float*)d_in[3];
    const float* Wf1 = (const float*)d_in[4];
    const float* bf1 = (const float*)d_in[5];
    const float* Wf2 = (const float*)d_in[6];
    const float* bf2 = (const float*)d_in[7];
    const float* Wg1 = (const float*)d_in[8];
    const float* bg1 = (const float*)d_in[9];
    const float* Wg2 = (const float*)d_in[10];
    const float* bg2 = (const float*)d_in[11];
    float* out = (float*)d_out;

    hipLaunchKernelGGL(sde_kernel, dim3(2048), dim3(128), 0, stream,
                       in_signal, x0v, noise, Wf1, bf1, Wf2, bf2,
                       Wg1, bg1, Wg2, bg2, out);
}

// Round 9
// 606.670 us; speedup vs baseline: 1.8317x; 1.8317x over previous
//
#include <hip/hip_runtime.h>

// SDE scan: B=2048 rows, T=512 steps, FS=32, FA=16, H=64.
// One wave per batch row; T-loop in-kernel (recurrence is per-row).
// R9: consolidation on the R7 skeleton (single wave, pk FMA). R8's cross-wave
//     split proved per-step barriers cost ~1350cy each -> reverted. R3 vs R7
//     showed a ~2100cy/step non-issue floor: serial chain + DS pipe. R9 trims
//     the chain with in-session-proven pieces, FMA order untouched (bit-exact):
//       1. shfl_xor+selects -> permlane32_swap (R4/R5-proven): removes the
//          last DS round trip from the x-update critical path.
//       2. eps pre-scaled at load (R4/R5-proven; same product grouping).
//       3. unconditional xbuf write (R4/R5-proven; 2-way same-value = free).
//       4. one-time s_sleep stagger on bit-10 blocks: de-phase co-resident
//          waves so their DS stalls interleave instead of aligning.
//     Predicted: absmax EXACTLY 0.0078125.

#define SQRT_DT_F 0.22360679774997896f

typedef float v2f __attribute__((ext_vector_type(2)));
typedef float v4f __attribute__((ext_vector_type(4)));
typedef int   v2i __attribute__((ext_vector_type(2)));

// Packed 2x fp32 FMA: per-element fmaf semantics; lowers to v_pk_fma_f32.
#define PK(acc, s, w) (acc) = __builtin_elementwise_fma((s), (w), (acc))

__device__ __forceinline__ float fast_tanh(float y) {
    // tanh(y) = 1 - 2/(exp(2y)+1); stable at both extremes
    float e = __expf(2.0f * y);
    return 1.0f - 2.0f / (e + 1.0f);
}

__device__ __forceinline__ void wave_sync() {
    // Single-wave block: DS pipe is in-order within a wave; we only need to
    // stop the compiler moving DS ops across this point. Everything else
    // (VALU/SALU/VMEM/trans) may cross freely.
    __builtin_amdgcn_fence(__ATOMIC_SEQ_CST, "wavefront");
    __builtin_amdgcn_sched_barrier(0x047F);
}

__global__ __launch_bounds__(64, 2)
void sde_kernel(const float* __restrict__ in_signal,   // (B,16,512)
                const float* __restrict__ x0v,         // (B,32)
                const float* __restrict__ noise,       // (511,B,32)
                const float* __restrict__ Wf1, const float* __restrict__ bf1,
                const float* __restrict__ Wf2, const float* __restrict__ bf2,
                const float* __restrict__ Wg1, const float* __restrict__ bg1,
                const float* __restrict__ Wg2, const float* __restrict__ bg2,
                float* __restrict__ out)               // (B,32,512)
{
    const int lane = threadIdx.x;   // 0..63
    const int b    = blockIdx.x;    // batch row

    __shared__ __align__(16) float hbuf[2][128];   // [parity][hf(64), hg(64)], sigma-permuted
    __shared__ __align__(16) float xbuf[32];       // broadcast x-state
    __shared__ __align__(16) float abuf[2][4][16]; // [quad parity][tt][k]

    // ---- weights -> registers as pk pairs (one-time, coalesced) ----
    // L1 pair k2 covers input indices (2k2, 2k2+1): matches acc chains (f0,f1).
    v2f w1fv[24], w1gv[24];
#pragma unroll
    for (int k2 = 0; k2 < 24; ++k2) {
        w1fv[k2] = v2f{Wf1[(2 * k2) * 64 + lane], Wf1[(2 * k2 + 1) * 64 + lane]};
        w1gv[k2] = v2f{Wg1[(2 * k2) * 64 + lane], Wg1[(2 * k2 + 1) * 64 + lane]};
    }
    // L2 pair (g,i) covers h indices (8g+i, 8g+4+i): matches chains (acc2a,acc2b).
    v2f w2v[32];
    const float* W2p = (lane < 32) ? (Wf2 + lane) : (Wg2 + (lane - 32));
#pragma unroll
    for (int g = 0; g < 8; ++g)
#pragma unroll
        for (int i = 0; i < 4; ++i)
            w2v[g * 4 + i] = v2f{W2p[(8 * g + i) * 32], W2p[(8 * g + 4 + i) * 32]};

    const float b1f = bf1[lane];
    const float b1g = bg1[lane];
    const float b2  = (lane < 32) ? bf2[lane] : bg2[lane - 32];

    // ---- state: x_{lane&31} identical in both wave halves ----
    float x_cur = x0v[b * 32 + (lane & 31)];
    xbuf[lane & 31] = x_cur;      // both halves, same value: free 2-way write
    float xq[4];
    xq[0] = x_cur;

    // sigma: position of h_j inside its 8-block so that (j, j+4) pairs are
    // adjacent in LDS. sigma(8g+r) = 8g + ((r&3)<<1 | r>>2).
    const int sig = (lane & ~7) | ((lane & 3) << 1) | ((lane >> 2) & 1);
    float* hw0 = &hbuf[0][sig];                          // hf slot, parity 0
    float* hw1 = &hbuf[1][sig];                          // parity 1
    const float* hsrc0 = hbuf[0] + ((lane >> 5) << 6);   // hf or hg, parity 0
    const float* hsrc1 = hbuf[1] + ((lane >> 5) << 6);   // parity 1
    const float* a_base = in_signal + ((size_t)(b * 16 + (lane & 15)) << 9);
    const float* noise_lane = noise + (size_t)b * 32 + (lane & 31);
    float* out_ptr = out + ((size_t)b * 32 + (lane & 31)) * 512;

    // prefetch eps two steps ahead, pre-scaled by sqrt(dt) at load
    float eps_c = noise_lane[0] * SQRT_DT_F;             // t = 0
    float eps_n = noise_lane[65536] * SQRT_DT_F;         // t = 1

    {   // quad 0 a-values -> abuf[0] (transposed by lanes 0-15)
        float4 a0 = *(const float4*)(a_base);
        if (lane < 16) {
            abuf[0][0][lane] = a0.x;
            abuf[0][1][lane] = a0.y;
            abuf[0][2][lane] = a0.z;
            abuf[0][3][lane] = a0.w;
        }
    }
    wave_sync();

    // De-phase: half the blocks (bit 10 -> likely different dispatch wrap on
    // the same SIMD) start ~1024cy late so co-resident waves' DS stalls
    // interleave instead of aligning. One-time, init only.
    if ((b >> 10) & 1) __builtin_amdgcn_s_sleep(16);

#define STEP(tt) do {                                                           \
    const int t_ = tq4 + (tt);                                                  \
    /* prefetch eps for step t+2 (~2 steps of latency cover), pre-scaled */     \
    int tf_ = t_ + 2; if (tf_ > 510) tf_ = 510;                                 \
    float eps_f = noise_lane[(size_t)tf_ << 16] * SQRT_DT_F;                    \
    /* layer-1 operands: batch LDS broadcast reads (12 ds_read_b128) */         \
    v4f sq[12];                                                                 \
    sq[0] = *(const v4f*)&ab_[tt][0];                                           \
    sq[1] = *(const v4f*)&ab_[tt][4];                                           \
    sq[2] = *(const v4f*)&ab_[tt][8];                                           \
    sq[3] = *(const v4f*)&ab_[tt][12];                                          \
    _Pragma("unroll")                                                           \
    for (int q = 0; q < 8; ++q)                                                 \
        sq[4 + q] = *(const v4f*)&xbuf[q * 4];                                  \
    /* layer 1: lane j -> hf_j, hg_j ; pk lanes = original (f0,f1)/(g0,g1) */   \
    v2f af = v2f{b1f, 0.f}, ag = v2f{b1g, 0.f};                                 \
    _Pragma("unroll")                                                           \
    for (int q = 0; q < 12; ++q) {                                              \
        v2f slo = sq[q].xy, shi = sq[q].zw;                                     \
        PK(af, slo, w1fv[2 * q]);                                               \
        PK(ag, slo, w1gv[2 * q]);                                               \
        PK(af, shi, w1fv[2 * q + 1]);                                           \
        PK(ag, shi, w1gv[2 * q + 1]);                                           \
    }                                                                           \
    float hfv = fast_tanh(af.x + af.y);                                         \
    float hgv = fast_tanh(ag.x + ag.y);                                         \
    {   /* sigma-permuted h write: conflict-free bijection per 8-block */       \
        float* hw_ = ((tt) & 1) ? hw1 : hw0;                                    \
        hw_[0]  = hfv;                                                          \
        hw_[64] = hgv;                                                          \
    }                                                                           \
    wave_sync();                                                                \
    /* layer 2: lanes 0-31 drift_i (hf), lanes 32-63 diff-pre_i (hg) */         \
    {                                                                           \
        const float* hs_ = ((tt) & 1) ? hsrc1 : hsrc0;                          \
        v2f a2 = v2f{b2, 0.f};   /* pk lanes = original (acc2a, acc2b) */       \
        _Pragma("unroll")                                                       \
        for (int g = 0; g < 8; ++g) {                                           \
            const v4f qa = *(const v4f*)&hs_[g * 8];                            \
            const v4f qb = *(const v4f*)&hs_[g * 8 + 4];                        \
            v2f p0 = qa.xy, p1 = qa.zw, p2 = qb.xy, p3 = qb.zw;                 \
            PK(a2, p0, w2v[g * 4 + 0]);                                         \
            PK(a2, p1, w2v[g * 4 + 1]);                                         \
            PK(a2, p2, w2v[g * 4 + 2]);                                         \
            PK(a2, p3, w2v[g * 4 + 3]);                                         \
        }                                                                       \
        float acc2 = a2.x + a2.y;                                               \
        /* swap halves in-register (VALU, no DS): pr.x = drift (all lanes),  */ \
        /* pr.y = gpre (all lanes). Proven bit-correct in R4/R5.             */ \
        v2i pr = __builtin_amdgcn_permlane32_swap(                              \
            __float_as_int(acc2), __float_as_int(acc2), false, false);          \
        const float drift = __int_as_float(pr.x);                               \
        const float gpre  = __int_as_float(pr.y);                               \
        float xi = fmaf(gpre, eps_c, drift);                                    \
        xi = fminf(5.0f, fmaxf(-5.0f, xi));                                     \
        xbuf[lane & 31] = xi;    /* both halves, same value: free 2-way */      \
        xq[((tt) + 1) & 3] = xi;                                                \
        if ((tt) == 2) {                                                        \
            if (lane < 32)                                                      \
                *(float4*)(out_ptr + tq4) =                                     \
                    make_float4(xq[0], xq[1], xq[2], xq[3]);                    \
        }                                                                       \
    }                                                                           \
    wave_sync();                                                                \
    eps_c = eps_n; eps_n = eps_f;                                               \
} while (0)

    // main: t = 0..507 (127 quads)
    for (int tq = 0; tq < 127; ++tq) {
        const int tq4 = tq * 4;
        const float (*ab_)[16] = abuf[tq & 1];
        float4 aq_n = *(const float4*)(a_base + tq4 + 4);   // quad tq+1
        STEP(0);
        // stage next quad's a-values (parity flip; current quad reads ab_)
        if (lane < 16) {
            float (*abn)[16] = abuf[(tq + 1) & 1];
            abn[0][lane] = aq_n.x;
            abn[1][lane] = aq_n.y;
            abn[2][lane] = aq_n.z;
            abn[3][lane] = aq_n.w;
        }
        STEP(1); STEP(2); STEP(3);
    }
    // tail: t = 508, 509, 510  (store of [508..511] fires at tt==2)
    {
        const int tq4 = 508;
        const float (*ab_)[16] = abuf[127 & 1];
        STEP(0); STEP(1); STEP(2);
    }
#undef STEP
}

extern "C" void kernel_launch(void* const* d_in, const int* in_sizes, int n_in,
                              void* d_out, int out_size, void* d_ws, size_t ws_size,
                              hipStream_t stream) {
    // inputs: 0 ts(unused), 1 in_signal, 2 x0, 3 noise, 4 Wf1, 5 bf1, 6 Wf2,
    //         7 bf2, 8 Wg1, 9 bg1, 10 Wg2, 11 bg2
    const float* in_signal = (const float*)d_in[1];
    const float* x0v   = (const float*)d_in[2];
    const float* noise = (const float*)d_in[3];
    const float* Wf1 = (const float*)d_in[4];
    const float* bf1 = (const float*)d_in[5];
    const float* Wf2 = (const float*)d_in[6];
    const float* bf2 = (const float*)d_in[7];
    const float* Wg1 = (const float*)d_in[8];
    const float* bg1 = (const float*)d_in[9];
    const float* Wg2 = (const float*)d_in[10];
    const float* bg2 = (const float*)d_in[11];
    float* out = (float*)d_out;

    hipLaunchKernelGGL(sde_kernel, dim3(2048), dim3(64), 0, stream,
                       in_signal, x0v, noise, Wf1, bf1, Wf2, bf2,
                       Wg1, bg1, Wg2, bg2, out);
}